// Round 4
// baseline (1122.177 us; speedup 1.0000x reference)
//
#include <hip/hip_runtime.h>

#define D_MODEL 1024
#define N_FEAT  16384
#define N_TOK   4096
#define K_TOP   64
#define CAND_MAX 192
#define DELTA    0.02f

#define BM 128
#define BN 128
#define BK 64

typedef __attribute__((ext_vector_type(8))) short bf16x8;
typedef __attribute__((ext_vector_type(4))) float f32x4;

// ---- monotonic float<->uint key ----
__device__ __forceinline__ unsigned fkey(float f) {
    unsigned b = __float_as_uint(f);
    return (b & 0x80000000u) ? ~b : (b | 0x80000000u);
}
__device__ __forceinline__ float kinv(unsigned k) {
    unsigned b = (k & 0x80000000u) ? (k ^ 0x80000000u) : ~k;
    return __uint_as_float(b);
}
// f32 -> bf16 round-to-nearest-even
__device__ __forceinline__ unsigned short f2bf(float f) {
    unsigned u = __float_as_uint(f);
    return (unsigned short)((u + 0x7FFFu + ((u >> 16) & 1u)) >> 16);
}
__device__ __forceinline__ float bf2f(unsigned short u) {
    return __uint_as_float(((unsigned)u) << 16);
}
__device__ __forceinline__ void gload_lds16(const void* g, void* l) {
    __builtin_amdgcn_global_load_lds(
        (const __attribute__((address_space(1))) void*)g,
        (__attribute__((address_space(3))) void*)l, 16, 0, 0);
}

// =====================================================================
// Prep: f32 -> bf16 (RNE), 4 elems/thread
// =====================================================================
__global__ __launch_bounds__(256)
void cvt_bf16(const float* __restrict__ s, unsigned short* __restrict__ d, int n4)
{
    int i = blockIdx.x * 256 + threadIdx.x;
    if (i < n4) {
        float4 v = ((const float4*)s)[i];
        ushort4 o;
        o.x = f2bf(v.x); o.y = f2bf(v.y); o.z = f2bf(v.z); o.w = f2bf(v.w);
        ((ushort4*)d)[i] = o;
    }
}

// =====================================================================
// Kernel 1 (fast path): bf16 MFMA encode GEMM, m97 structure.
// =====================================================================
__global__ __launch_bounds__(256)
void encode_mfma(const unsigned short* __restrict__ Xb,
                 const unsigned short* __restrict__ Wb,
                 const float* __restrict__ be, float* __restrict__ h)
{
    __shared__ unsigned short Al[BM * BK];
    __shared__ unsigned short Bl[BN * BK];

    const int nwg = gridDim.x;
    const int per = nwg >> 3;
    const int sw  = (blockIdx.x & 7) * per + (blockIdx.x >> 3);
    const int bm  = sw / (N_FEAT / BN);
    const int bn  = sw % (N_FEAT / BN);

    const int tid  = threadIdx.x;
    const int wid  = tid >> 6;
    const int lane = tid & 63;
    const int wr   = wid >> 1, wc = wid & 1;

    const size_t Abase = (size_t)(bm * BM) * D_MODEL;
    const size_t Bbase = (size_t)(bn * BN) * D_MODEL;

    f32x4 acc[4][4];
    #pragma unroll
    for (int m = 0; m < 4; ++m)
        #pragma unroll
        for (int n = 0; n < 4; ++n)
            acc[m][n] = (f32x4){0.f, 0.f, 0.f, 0.f};

    const int srow = (lane >> 3);
    const int scol = (lane & 7) * 8;

    for (int k0 = 0; k0 < D_MODEL; k0 += BK) {
        #pragma unroll
        for (int c4 = 0; c4 < 4; ++c4) {
            const int c   = wid * 4 + c4;
            const int row = c * 8 + srow;
            gload_lds16(Xb + Abase + (size_t)row * D_MODEL + k0 + scol, &Al[c * 512]);
            gload_lds16(Wb + Bbase + (size_t)row * D_MODEL + k0 + scol, &Bl[c * 512]);
        }
        __syncthreads();

        bf16x8 af[2][4], bf[2][4];
        const int kc = (lane >> 4) * 8;
        #pragma unroll
        for (int ks = 0; ks < 2; ++ks) {
            #pragma unroll
            for (int m = 0; m < 4; ++m)
                af[ks][m] = *(const bf16x8*)&Al[(wr * 64 + m * 16 + (lane & 15)) * BK + ks * 32 + kc];
            #pragma unroll
            for (int n = 0; n < 4; ++n)
                bf[ks][n] = *(const bf16x8*)&Bl[(wc * 64 + n * 16 + (lane & 15)) * BK + ks * 32 + kc];
        }
        #pragma unroll
        for (int ks = 0; ks < 2; ++ks)
            #pragma unroll
            for (int m = 0; m < 4; ++m)
                #pragma unroll
                for (int n = 0; n < 4; ++n)
                    acc[m][n] = __builtin_amdgcn_mfma_f32_16x16x32_bf16(af[ks][m], bf[ks][n], acc[m][n], 0, 0, 0);
        __syncthreads();
    }

    const int c0 = bn * BN + wc * 64 + (lane & 15);
    #pragma unroll
    for (int m = 0; m < 4; ++m) {
        const int r0 = bm * BM + wr * 64 + m * 16 + (lane >> 4) * 4;
        #pragma unroll
        for (int n = 0; n < 4; ++n) {
            const int col = c0 + n * 16;
            const float bias = be[col];
            #pragma unroll
            for (int r = 0; r < 4; ++r)
                h[(size_t)(r0 + r) * N_FEAT + col] = acc[m][n][r] + bias;
        }
    }
}

// =====================================================================
// Kernel 1 (fallback): f32 vector-ALU tiled GEMM
// =====================================================================
__global__ __launch_bounds__(256)
void encode_gemm(const float* __restrict__ x, const float* __restrict__ W,
                 const float* __restrict__ be, float* __restrict__ h)
{
    __shared__ float As[32][68];
    __shared__ float Bs[32][68];

    const int bm = blockIdx.x % (N_TOK / 64);
    const int bn = blockIdx.x / (N_TOK / 64);
    const int tid = threadIdx.x;
    const int tx = tid & 15, ty = tid >> 4;

    const float* Ab = x + (size_t)(bm * 64) * D_MODEL;
    const float* Bb = W + (size_t)(bn * 64) * D_MODEL;

    float acc[4][4] = {};

    for (int k0 = 0; k0 < D_MODEL; k0 += 32) {
        #pragma unroll
        for (int i = 0; i < 8; ++i) {
            int e = tid + i * 256;
            int kk = e & 31, m = e >> 5;
            As[kk][m] = Ab[(size_t)m * D_MODEL + k0 + kk];
            Bs[kk][m] = Bb[(size_t)m * D_MODEL + k0 + kk];
        }
        __syncthreads();
        #pragma unroll
        for (int kk = 0; kk < 32; ++kk) {
            float4 a4 = *(const float4*)&As[kk][ty * 4];
            float4 b4 = *(const float4*)&Bs[kk][tx * 4];
            float a[4] = {a4.x, a4.y, a4.z, a4.w};
            float b[4] = {b4.x, b4.y, b4.z, b4.w};
            #pragma unroll
            for (int i = 0; i < 4; ++i)
                #pragma unroll
                for (int j = 0; j < 4; ++j)
                    acc[i][j] = fmaf(a[i], b[j], acc[i][j]);
        }
        __syncthreads();
    }

    const int rowb = bm * 64 + ty * 4;
    const int colb = bn * 64 + tx * 4;
    float4 bev = *(const float4*)&be[colb];
    float bb[4] = {bev.x, bev.y, bev.z, bev.w};
    #pragma unroll
    for (int i = 0; i < 4; ++i) {
        float4 o;
        o.x = acc[i][0] + bb[0];
        o.y = acc[i][1] + bb[1];
        o.z = acc[i][2] + bb[2];
        o.w = acc[i][3] + bb[3];
        *(float4*)&h[(size_t)(rowb + i) * N_FEAT + colb] = o;
    }
}

// =====================================================================
// Kernel 2: per-row top-64.
//  - radix select T (f32 64th-largest)
//  - sure set: h > T+DELTA (provably in top-64); ambiguous: |h-T| <= DELTA
//  - f64 refinement of AMBIGUOUS ONLY; exact deterministic slot assignment
//  - streaming zero+scatter write of sparse row; decode from bf16 W if avail
// =====================================================================
template<bool USE_WB>
__global__ __launch_bounds__(256)
void topk_decode(const float* __restrict__ hsrc,
                 const float* __restrict__ x, const float* __restrict__ W,
                 const unsigned short* __restrict__ Wb,
                 const float* __restrict__ be, const float* __restrict__ bd,
                 float* __restrict__ out)
{
    const int row = blockIdx.x;
    const int tid = threadIdx.x;
    float* recon = out + (size_t)row * D_MODEL;
    float* srow  = out + (size_t)N_TOK * D_MODEL + (size_t)row * N_FEAT;
    const float* hr = hsrc + (size_t)row * N_FEAT;

    unsigned key[16][4];
    #pragma unroll
    for (int i = 0; i < 16; ++i) {
        float4 v = ((const float4*)hr)[tid + i * 256];
        key[i][0] = fkey(v.x); key[i][1] = fkey(v.y);
        key[i][2] = fkey(v.z); key[i][3] = fkey(v.w);
    }

    __shared__ unsigned hist[256];
    __shared__ unsigned sh_prefix;
    __shared__ int sh_need;
    __shared__ float xs[D_MODEL];
    __shared__ int      cand_idx[CAND_MAX];
    __shared__ unsigned cand_key[CAND_MAX];
    __shared__ double   cand_val[CAND_MAX];
    __shared__ int nc_sh, nsure_sh;
    __shared__ int   tk_idx[K_TOP];
    __shared__ float tk_val[K_TOP];

    *(float4*)&xs[tid * 4] = *(const float4*)&x[(size_t)row * D_MODEL + tid * 4];
    if (tid == 0) { nc_sh = 0; nsure_sh = 0; }
    if (tid < K_TOP) { tk_val[tid] = 0.0f; tk_idx[tid] = -1; }

    // ---- radix select: T = exact f32 64th-largest key
    unsigned prefix = 0, maskv = 0;
    int need = K_TOP;
    for (int pass = 0; pass < 4; ++pass) {
        const int shift = 24 - 8 * pass;
        hist[tid] = 0;
        __syncthreads();
        #pragma unroll
        for (int i = 0; i < 16; ++i)
            #pragma unroll
            for (int j = 0; j < 4; ++j) {
                unsigned k = key[i][j];
                if ((k & maskv) == prefix)
                    atomicAdd(&hist[(k >> shift) & 255u], 1u);
            }
        __syncthreads();
        if (tid == 0) {
            unsigned cum = 0;
            int d = 255;
            for (; d >= 0; --d) {
                unsigned c = hist[d];
                if (cum + c >= (unsigned)need) break;
                cum += c;
            }
            if (d < 0) d = 0;
            sh_need = need - (int)cum;
            sh_prefix = prefix | ((unsigned)d << shift);
        }
        __syncthreads();
        prefix = sh_prefix;
        need = sh_need;
        maskv |= (0xFFu << shift);
    }
    const unsigned T  = prefix;
    const unsigned Tl = fkey(kinv(T) - DELTA);
    const unsigned Th = fkey(kinv(T) + DELTA);

    // ---- candidates: key >= Tl  (true top-64 always inside; nc >= 64)
    #pragma unroll
    for (int i = 0; i < 16; ++i)
        #pragma unroll
        for (int j = 0; j < 4; ++j)
            if (key[i][j] >= Tl) {
                int p = atomicAdd(&nc_sh, 1);
                if (p < CAND_MAX) {
                    cand_idx[p] = (tid + i * 256) * 4 + j;
                    cand_key[p] = key[i][j];
                }
            }
    __syncthreads();
    int nc = nc_sh; if (nc > CAND_MAX) nc = CAND_MAX;

    if (tid < nc && cand_key[tid] > Th) atomicAdd(&nsure_sh, 1);
    __syncthreads();
    const int n_sure = nsure_sh;

    // ---- f64 refinement: AMBIGUOUS candidates only (key <= Th)
    {
        const int lane = tid & 63, wave = tid >> 6;
        for (int c = wave; c < nc; c += 4) {
            if (cand_key[c] > Th) continue;            // uniform per c
            const float* wr = &W[(size_t)cand_idx[c] * D_MODEL];
            double s = 0.0;
            #pragma unroll
            for (int e = 0; e < 16; ++e) {
                int d = lane + e * 64;                 // conflict-free LDS, coalesced W
                s += (double)xs[d] * (double)wr[d];
            }
            #pragma unroll
            for (int o = 32; o; o >>= 1) s += __shfl_down(s, o);
            if (lane == 0) cand_val[c] = s + (double)be[cand_idx[c]];
        }
    }
    __syncthreads();

    // ---- deterministic slot assignment
    if (tid < nc) {
        const unsigned ki = cand_key[tid];
        const int fi = cand_idx[tid];
        if (ki > Th) {
            // sure: rank among sure by index asc
            int r = 0;
            for (int j = 0; j < nc; ++j)
                r += (cand_key[j] > Th) && (cand_idx[j] < fi);
            tk_idx[r] = fi;
            tk_val[r] = fmaxf(kinv(ki), 0.0f);
        } else {
            // ambiguous: rank by refined f64 value desc, index asc
            const double v = cand_val[tid];
            int r = 0;
            for (int j = 0; j < nc; ++j) {
                if (cand_key[j] > Th) continue;
                double vj = cand_val[j];
                r += (vj > v) || (vj == v && cand_idx[j] < fi);
            }
            if (r < K_TOP - n_sure) {
                tk_idx[n_sure + r] = fi;
                tk_val[n_sure + r] = fmaxf((float)v, 0.0f);
            }
        }
    }
    __syncthreads();

    // ---- streaming write of sparse row (zeros + selected values)
    #pragma unroll
    for (int i = 0; i < 16; ++i) {
        float ov[4];
        #pragma unroll
        for (int j = 0; j < 4; ++j) {
            unsigned k = key[i][j];
            int f = (tid + i * 256) * 4 + j;
            float val = 0.0f;
            if (k >= Tl) {                              // rare (~70/16384)
                for (int q = 0; q < K_TOP; ++q)
                    if (tk_idx[q] == f) { val = tk_val[q]; break; }
            }
            ov[j] = val;
        }
        float4 o; o.x = ov[0]; o.y = ov[1]; o.z = ov[2]; o.w = ov[3];
        ((float4*)srow)[tid + i * 256] = o;
    }
    __syncthreads();

    // ---- decode: recon[d] = b_dec[d] + sum_j tk_val[j] * W[tk_idx[j]][d]
    const int d4 = tid * 4;
    float4 a = *(const float4*)&bd[d4];
    if (USE_WB) {
        #pragma unroll 8
        for (int j = 0; j < K_TOP; ++j) {
            float v = tk_val[j];
            ushort4 w4 = *(const ushort4*)&Wb[(size_t)tk_idx[j] * D_MODEL + d4];
            a.x = fmaf(v, bf2f(w4.x), a.x);
            a.y = fmaf(v, bf2f(w4.y), a.y);
            a.z = fmaf(v, bf2f(w4.z), a.z);
            a.w = fmaf(v, bf2f(w4.w), a.w);
        }
    } else {
        #pragma unroll 8
        for (int j = 0; j < K_TOP; ++j) {
            float v = tk_val[j];
            const float4 w = *(const float4*)&W[(size_t)tk_idx[j] * D_MODEL + d4];
            a.x = fmaf(v, w.x, a.x);
            a.y = fmaf(v, w.y, a.y);
            a.z = fmaf(v, w.z, a.z);
            a.w = fmaf(v, w.w, a.w);
        }
    }
    *(float4*)&recon[d4] = a;
}

extern "C" void kernel_launch(void* const* d_in, const int* in_sizes, int n_in,
                              void* d_out, int out_size, void* d_ws, size_t ws_size,
                              hipStream_t stream) {
    const float* x     = (const float*)d_in[0];
    const float* W_enc = (const float*)d_in[1];
    const float* b_enc = (const float*)d_in[2];
    const float* b_dec = (const float*)d_in[4];
    float* out = (float*)d_out;

    float* h_out_region = out + (size_t)N_TOK * D_MODEL;

    const size_t nx = (size_t)N_TOK * D_MODEL;
    const size_t nw = (size_t)N_FEAT * D_MODEL;
    const size_t bf_bytes = (nx + nw) * sizeof(unsigned short);        // 40 MB
    const size_t h_bytes  = (size_t)N_TOK * N_FEAT * sizeof(float);    // 256 MB

    if (ws_size >= bf_bytes) {
        unsigned short* Xb = (unsigned short*)d_ws;
        unsigned short* Wb = Xb + nx;
        cvt_bf16<<<(int)(nx / 4 / 256), 256, 0, stream>>>(x, Xb, (int)(nx / 4));
        cvt_bf16<<<(int)(nw / 4 / 256), 256, 0, stream>>>(W_enc, Wb, (int)(nw / 4));

        float* h = (ws_size >= bf_bytes + h_bytes)
                       ? (float*)((char*)d_ws + bf_bytes)   // tier A: h in ws
                       : h_out_region;                       // tier B: in-place
        encode_mfma<<<(N_TOK / BM) * (N_FEAT / BN), 256, 0, stream>>>(Xb, Wb, b_enc, h);
        topk_decode<true><<<N_TOK, 256, 0, stream>>>(h, x, W_enc, Wb, b_enc, b_dec, out);
    } else {
        encode_gemm<<<(N_TOK / 64) * (N_FEAT / 64), 256, 0, stream>>>(x, W_enc, b_enc, h_out_region);
        topk_decode<false><<<N_TOK, 256, 0, stream>>>(h_out_region, x, W_enc, nullptr, b_enc, b_dec, out);
    }
}

// Round 5
// 1014.740 us; speedup vs baseline: 1.1059x; 1.1059x over previous
//
#include <hip/hip_runtime.h>

#define D_MODEL 1024
#define N_FEAT  16384
#define N_TOK   4096
#define K_TOP   64
#define CAND_MAX 256
#define DELTA    0.03f

#define BM 128
#define BN 128
#define BK 64

typedef __attribute__((ext_vector_type(8))) short bf16x8;
typedef __attribute__((ext_vector_type(8))) unsigned short u16x8;
typedef __attribute__((ext_vector_type(4))) float f32x4;

// ---- monotonic float<->uint keys ----
__device__ __forceinline__ unsigned fkey(float f) {
    unsigned b = __float_as_uint(f);
    return (b & 0x80000000u) ? ~b : (b | 0x80000000u);
}
__device__ __forceinline__ float kinv(unsigned k) {
    unsigned b = (k & 0x80000000u) ? (k ^ 0x80000000u) : ~k;
    return __uint_as_float(b);
}
// f32 -> bf16 bits, RNE
__device__ __forceinline__ unsigned short f2bf(float f) {
    unsigned u = __float_as_uint(f);
    return (unsigned short)((u + 0x7FFFu + ((u >> 16) & 1u)) >> 16);
}
__device__ __forceinline__ float bf2f(unsigned u) {
    return __uint_as_float(u << 16);
}
// 16-bit monotonic key over bf16 bits
__device__ __forceinline__ unsigned fkey16(unsigned b) {
    return (b & 0x8000u) ? (~b & 0xFFFFu) : (b | 0x8000u);
}
__device__ __forceinline__ float kval16(unsigned k) {
    unsigned b = (k & 0x8000u) ? (k ^ 0x8000u) : (~k & 0xFFFFu);
    return bf2f(b);
}
__device__ __forceinline__ unsigned fkey16f(float v) { return fkey16((unsigned)f2bf(v)); }

__device__ __forceinline__ void gload_lds16(const void* g, void* l) {
    __builtin_amdgcn_global_load_lds(
        (const __attribute__((address_space(1))) void*)g,
        (__attribute__((address_space(3))) void*)l, 16, 0, 0);
}

// =====================================================================
// Prep: f32 -> bf16 (RNE)
// =====================================================================
__global__ __launch_bounds__(256)
void cvt_bf16(const float* __restrict__ s, unsigned short* __restrict__ d, int n4)
{
    int i = blockIdx.x * 256 + threadIdx.x;
    if (i < n4) {
        float4 v = ((const float4*)s)[i];
        ushort4 o;
        o.x = f2bf(v.x); o.y = f2bf(v.y); o.z = f2bf(v.z); o.w = f2bf(v.w);
        ((ushort4*)d)[i] = o;
    }
}

// =====================================================================
// Kernel 1: bf16 MFMA encode GEMM (m97 structure); h out as bf16 or f32
// =====================================================================
template<bool B16OUT>
__global__ __launch_bounds__(256)
void encode_mfma(const unsigned short* __restrict__ Xb,
                 const unsigned short* __restrict__ Wb,
                 const float* __restrict__ be, void* __restrict__ hout)
{
    __shared__ unsigned short Al[BM * BK];
    __shared__ unsigned short Bl[BN * BK];

    const int nwg = gridDim.x;
    const int per = nwg >> 3;
    const int sw  = (blockIdx.x & 7) * per + (blockIdx.x >> 3);
    const int bm  = sw / (N_FEAT / BN);
    const int bn  = sw % (N_FEAT / BN);

    const int tid  = threadIdx.x;
    const int wid  = tid >> 6;
    const int lane = tid & 63;
    const int wr   = wid >> 1, wc = wid & 1;

    const size_t Abase = (size_t)(bm * BM) * D_MODEL;
    const size_t Bbase = (size_t)(bn * BN) * D_MODEL;

    f32x4 acc[4][4];
    #pragma unroll
    for (int m = 0; m < 4; ++m)
        #pragma unroll
        for (int n = 0; n < 4; ++n)
            acc[m][n] = (f32x4){0.f, 0.f, 0.f, 0.f};

    const int srow = (lane >> 3);
    const int scol = (lane & 7) * 8;

    for (int k0 = 0; k0 < D_MODEL; k0 += BK) {
        #pragma unroll
        for (int c4 = 0; c4 < 4; ++c4) {
            const int c   = wid * 4 + c4;
            const int row = c * 8 + srow;
            gload_lds16(Xb + Abase + (size_t)row * D_MODEL + k0 + scol, &Al[c * 512]);
            gload_lds16(Wb + Bbase + (size_t)row * D_MODEL + k0 + scol, &Bl[c * 512]);
        }
        __syncthreads();

        bf16x8 af[2][4], bf[2][4];
        const int kc = (lane >> 4) * 8;
        #pragma unroll
        for (int ks = 0; ks < 2; ++ks) {
            #pragma unroll
            for (int m = 0; m < 4; ++m)
                af[ks][m] = *(const bf16x8*)&Al[(wr * 64 + m * 16 + (lane & 15)) * BK + ks * 32 + kc];
            #pragma unroll
            for (int n = 0; n < 4; ++n)
                bf[ks][n] = *(const bf16x8*)&Bl[(wc * 64 + n * 16 + (lane & 15)) * BK + ks * 32 + kc];
        }
        #pragma unroll
        for (int ks = 0; ks < 2; ++ks)
            #pragma unroll
            for (int m = 0; m < 4; ++m)
                #pragma unroll
                for (int n = 0; n < 4; ++n)
                    acc[m][n] = __builtin_amdgcn_mfma_f32_16x16x32_bf16(af[ks][m], bf[ks][n], acc[m][n], 0, 0, 0);
        __syncthreads();
    }

    const int c0 = bn * BN + wc * 64 + (lane & 15);
    #pragma unroll
    for (int m = 0; m < 4; ++m) {
        const int r0 = bm * BM + wr * 64 + m * 16 + (lane >> 4) * 4;
        #pragma unroll
        for (int n = 0; n < 4; ++n) {
            const int col = c0 + n * 16;
            const float bias = be[col];
            #pragma unroll
            for (int r = 0; r < 4; ++r) {
                float v = acc[m][n][r] + bias;
                if (B16OUT)
                    ((unsigned short*)hout)[(size_t)(r0 + r) * N_FEAT + col] = f2bf(v);
                else
                    ((float*)hout)[(size_t)(r0 + r) * N_FEAT + col] = v;
            }
        }
    }
}

// =====================================================================
// Kernel 1 (fallback): f32 vector-ALU tiled GEMM
// =====================================================================
__global__ __launch_bounds__(256)
void encode_gemm(const float* __restrict__ x, const float* __restrict__ W,
                 const float* __restrict__ be, float* __restrict__ h)
{
    __shared__ float As[32][68];
    __shared__ float Bs[32][68];

    const int bm = blockIdx.x % (N_TOK / 64);
    const int bn = blockIdx.x / (N_TOK / 64);
    const int tid = threadIdx.x;
    const int tx = tid & 15, ty = tid >> 4;

    const float* Ab = x + (size_t)(bm * 64) * D_MODEL;
    const float* Bb = W + (size_t)(bn * 64) * D_MODEL;

    float acc[4][4] = {};

    for (int k0 = 0; k0 < D_MODEL; k0 += 32) {
        #pragma unroll
        for (int i = 0; i < 8; ++i) {
            int e = tid + i * 256;
            int kk = e & 31, m = e >> 5;
            As[kk][m] = Ab[(size_t)m * D_MODEL + k0 + kk];
            Bs[kk][m] = Bb[(size_t)m * D_MODEL + k0 + kk];
        }
        __syncthreads();
        #pragma unroll
        for (int kk = 0; kk < 32; ++kk) {
            float4 a4 = *(const float4*)&As[kk][ty * 4];
            float4 b4 = *(const float4*)&Bs[kk][tx * 4];
            float a[4] = {a4.x, a4.y, a4.z, a4.w};
            float b[4] = {b4.x, b4.y, b4.z, b4.w};
            #pragma unroll
            for (int i = 0; i < 4; ++i)
                #pragma unroll
                for (int j = 0; j < 4; ++j)
                    acc[i][j] = fmaf(a[i], b[j], acc[i][j]);
        }
        __syncthreads();
    }

    const int rowb = bm * 64 + ty * 4;
    const int colb = bn * 64 + tx * 4;
    float4 bev = *(const float4*)&be[colb];
    float bb[4] = {bev.x, bev.y, bev.z, bev.w};
    #pragma unroll
    for (int i = 0; i < 4; ++i) {
        float4 o;
        o.x = acc[i][0] + bb[0];
        o.y = acc[i][1] + bb[1];
        o.z = acc[i][2] + bb[2];
        o.w = acc[i][3] + bb[3];
        *(float4*)&h[(size_t)(rowb + i) * N_FEAT + colb] = o;
    }
}

// ---- wave-0 suffix-scan bin select: 256 bins, 4/lane, shfl suffix scan ----
__device__ __forceinline__ void wave_select(unsigned* hist, int* sh_need, int* sh_bin, int lane)
{
    unsigned v0 = hist[lane * 4 + 0], v1 = hist[lane * 4 + 1];
    unsigned v2 = hist[lane * 4 + 2], v3 = hist[lane * 4 + 3];
    unsigned l3 = v3, l2 = v2 + l3, l1 = v1 + l2, l0 = v0 + l1;
    unsigned t = l0, acc = t;
    #pragma unroll
    for (int off = 1; off < 64; off <<= 1) {
        unsigned o = __shfl_down(acc, off);
        if (lane + off < 64) acc += o;
    }
    const unsigned E = acc - t;               // sum over lanes > lane
    const unsigned need = (unsigned)*sh_need; // all lanes read before any write
    const unsigned suf[4] = {l0 + E, l1 + E, l2 + E, l3 + E};
    const unsigned nxt[4] = {l1 + E, l2 + E, l3 + E, E};
    #pragma unroll
    for (int j = 0; j < 4; ++j)
        if (suf[j] >= need && nxt[j] < need) {
            *sh_bin = lane * 4 + j;
            *sh_need = (int)(need - nxt[j]);
        }
}

// =====================================================================
// Kernel 2 (fast): per-row top-64 from bf16 h. 1024 threads/row.
//  2-pass 8-bit radix over 16-bit keys, wave-0 shuffle bin select,
//  f64 refinement of the +/-DELTA band, grouped decode with LDS reduce.
// =====================================================================
__global__ __launch_bounds__(1024, 8)
void topk_decode16(const unsigned short* __restrict__ hb,
                   const float* __restrict__ x, const float* __restrict__ W,
                   const unsigned short* __restrict__ Wb,
                   const float* __restrict__ be, const float* __restrict__ bd,
                   float* __restrict__ out)
{
    const int row  = blockIdx.x;
    const int tid  = threadIdx.x;
    const int lane = tid & 63, wid = tid >> 6;

    float* recon = out + (size_t)row * D_MODEL;
    float* srow  = out + (size_t)N_TOK * D_MODEL + (size_t)row * N_FEAT;
    const unsigned short* hr = hb + (size_t)row * N_FEAT;

    __shared__ unsigned hist[256];
    __shared__ float xs[D_MODEL];
    __shared__ int      cand_idx[CAND_MAX];
    __shared__ unsigned cand_key[CAND_MAX];
    __shared__ double   cand_val[CAND_MAX];
    __shared__ int   tk_idx[K_TOP];
    __shared__ float tk_val[K_TOP];
    __shared__ f32x4 part[4][256];
    __shared__ int sh_need, sh_bin, nc_sh, nsure_sh;

    // ---- load 16 bf16 h elems -> 16-bit monotonic keys
    unsigned key[16];
    {
        u16x8 a = *(const u16x8*)&hr[tid * 16];
        u16x8 b = *(const u16x8*)&hr[tid * 16 + 8];
        #pragma unroll
        for (int j = 0; j < 8; ++j) {
            key[j]     = fkey16((unsigned)(unsigned short)a[j]);
            key[8 + j] = fkey16((unsigned)(unsigned short)b[j]);
        }
    }
    if (tid < 256) {
        *(float4*)&xs[tid * 4] = *(const float4*)&x[(size_t)row * D_MODEL + tid * 4];
        hist[tid] = 0;
    }
    if (tid == 0) { sh_need = K_TOP; nc_sh = 0; nsure_sh = 0; }
    if (tid < K_TOP) { tk_idx[tid] = 0; tk_val[tid] = 0.f; }
    __syncthreads();

    // ---- pass 1: high byte
    #pragma unroll
    for (int i = 0; i < 16; ++i) atomicAdd(&hist[key[i] >> 8], 1u);
    __syncthreads();
    if (wid == 0) wave_select(hist, &sh_need, &sh_bin, lane);
    __syncthreads();
    const unsigned hb_sel = (unsigned)sh_bin;
    if (tid < 256) hist[tid] = 0;
    __syncthreads();

    // ---- pass 2: low byte within selected high bin
    #pragma unroll
    for (int i = 0; i < 16; ++i)
        if ((key[i] >> 8) == hb_sel) atomicAdd(&hist[key[i] & 255u], 1u);
    __syncthreads();
    if (wid == 0) wave_select(hist, &sh_need, &sh_bin, lane);
    __syncthreads();

    const unsigned T    = (hb_sel << 8) | (unsigned)sh_bin;
    const float    Tval = kval16(T);
    const unsigned Tl   = fkey16f(Tval - DELTA);
    const unsigned Th   = fkey16f(Tval + DELTA);

    // ---- collect candidates: key >= Tl (true top-64 always inside)
    #pragma unroll
    for (int i = 0; i < 16; ++i)
        if (key[i] >= Tl) {
            int p = atomicAdd(&nc_sh, 1);
            if (p < CAND_MAX) {
                cand_idx[p] = tid * 16 + i;
                cand_key[p] = key[i];
            }
        }
    __syncthreads();
    int nc = nc_sh; if (nc > CAND_MAX) nc = CAND_MAX;
    if (tid < nc && cand_key[tid] > Th) atomicAdd(&nsure_sh, 1);
    __syncthreads();
    const int n_sure = nsure_sh;

    // ---- f64 refinement of the ambiguous band only (from exact f32 inputs)
    for (int c = wid; c < nc; c += 16) {
        if (cand_key[c] > Th) continue;
        const float* wr = &W[(size_t)cand_idx[c] * D_MODEL];
        double s = 0.0;
        #pragma unroll
        for (int e = 0; e < 16; ++e) {
            int d = lane + e * 64;
            s += (double)xs[d] * (double)wr[d];
        }
        #pragma unroll
        for (int o = 32; o; o >>= 1) s += __shfl_down(s, o);
        if (lane == 0) cand_val[c] = s + (double)be[cand_idx[c]];
    }
    __syncthreads();

    // ---- deterministic slot assignment
    if (tid < nc) {
        const unsigned ki = cand_key[tid];
        const int fi = cand_idx[tid];
        if (ki > Th) {                       // provably in top-64
            int r = 0;
            for (int j = 0; j < nc; ++j)
                r += (cand_key[j] > Th) && (cand_idx[j] < fi);
            tk_idx[r] = fi;
            tk_val[r] = fmaxf(kval16(ki), 0.f);
        } else {                             // exact f64 rank in the band
            const double v = cand_val[tid];
            int r = 0;
            for (int j = 0; j < nc; ++j) {
                if (cand_key[j] > Th) continue;
                double vj = cand_val[j];
                r += (vj > v) || (vj == v && cand_idx[j] < fi);
            }
            if (r < K_TOP - n_sure) {
                tk_idx[n_sure + r] = fi;
                tk_val[n_sure + r] = fmaxf((float)v, 0.f);
            }
        }
    }
    __syncthreads();

    // ---- streaming sparse-row write (zeros + selected values)
    #pragma unroll
    for (int q = 0; q < 4; ++q) {
        float ov[4];
        #pragma unroll
        for (int j = 0; j < 4; ++j) {
            unsigned k = key[q * 4 + j];
            float val = 0.f;
            if (k >= Tl) {                   // rare (~95/16384)
                int f = tid * 16 + q * 4 + j;
                for (int m = 0; m < K_TOP; ++m)
                    if (tk_idx[m] == f) { val = tk_val[m]; break; }
            }
            ov[j] = val;
        }
        float4 o; o.x = ov[0]; o.y = ov[1]; o.z = ov[2]; o.w = ov[3];
        ((float4*)srow)[tid * 4 + q] = o;
    }

    // ---- decode: 4 groups x 16 rows, LDS partial reduce
    {
        const int g = tid >> 8, t = tid & 255;
        const int d4 = t * 4;
        f32x4 a = (f32x4){0.f, 0.f, 0.f, 0.f};
        #pragma unroll 4
        for (int jj = 0; jj < 16; ++jj) {
            const int j = g * 16 + jj;
            const float v = tk_val[j];
            ushort4 w4 = *(const ushort4*)&Wb[(size_t)tk_idx[j] * D_MODEL + d4];
            a[0] = fmaf(v, bf2f((unsigned)w4.x), a[0]);
            a[1] = fmaf(v, bf2f((unsigned)w4.y), a[1]);
            a[2] = fmaf(v, bf2f((unsigned)w4.z), a[2]);
            a[3] = fmaf(v, bf2f((unsigned)w4.w), a[3]);
        }
        part[g][t] = a;
    }
    __syncthreads();
    if (tid < 256) {
        f32x4 r = part[0][tid];
        #pragma unroll
        for (int g = 1; g < 4; ++g) {
            f32x4 p = part[g][tid];
            r[0] += p[0]; r[1] += p[1]; r[2] += p[2]; r[3] += p[3];
        }
        float4 bdv = *(const float4*)&bd[tid * 4];
        float4 o;
        o.x = r[0] + bdv.x; o.y = r[1] + bdv.y;
        o.z = r[2] + bdv.z; o.w = r[3] + bdv.w;
        *(float4*)&recon[tid * 4] = o;
    }
}

// =====================================================================
// Kernel 2 (fallback, f32 h): round-4 structure, 256 threads/row
// =====================================================================
template<bool USE_WB>
__global__ __launch_bounds__(256)
void topk_decode(const float* __restrict__ hsrc,
                 const float* __restrict__ x, const float* __restrict__ W,
                 const unsigned short* __restrict__ Wb,
                 const float* __restrict__ be, const float* __restrict__ bd,
                 float* __restrict__ out)
{
    const int row = blockIdx.x;
    const int tid = threadIdx.x;
    float* recon = out + (size_t)row * D_MODEL;
    float* srow  = out + (size_t)N_TOK * D_MODEL + (size_t)row * N_FEAT;
    const float* hr = hsrc + (size_t)row * N_FEAT;

    unsigned key[16][4];
    #pragma unroll
    for (int i = 0; i < 16; ++i) {
        float4 v = ((const float4*)hr)[tid + i * 256];
        key[i][0] = fkey(v.x); key[i][1] = fkey(v.y);
        key[i][2] = fkey(v.z); key[i][3] = fkey(v.w);
    }

    __shared__ unsigned hist[256];
    __shared__ unsigned sh_prefix;
    __shared__ int sh_need;
    __shared__ float xs[D_MODEL];
    __shared__ int      cand_idx[CAND_MAX];
    __shared__ unsigned cand_key[CAND_MAX];
    __shared__ double   cand_val[CAND_MAX];
    __shared__ int nc_sh, nsure_sh;
    __shared__ int   tk_idx[K_TOP];
    __shared__ float tk_val[K_TOP];

    *(float4*)&xs[tid * 4] = *(const float4*)&x[(size_t)row * D_MODEL + tid * 4];
    if (tid == 0) { nc_sh = 0; nsure_sh = 0; }
    if (tid < K_TOP) { tk_val[tid] = 0.0f; tk_idx[tid] = -1; }

    unsigned prefix = 0, maskv = 0;
    int need = K_TOP;
    for (int pass = 0; pass < 4; ++pass) {
        const int shift = 24 - 8 * pass;
        hist[tid] = 0;
        __syncthreads();
        #pragma unroll
        for (int i = 0; i < 16; ++i)
            #pragma unroll
            for (int j = 0; j < 4; ++j) {
                unsigned k = key[i][j];
                if ((k & maskv) == prefix)
                    atomicAdd(&hist[(k >> shift) & 255u], 1u);
            }
        __syncthreads();
        if (tid == 0) {
            unsigned cum = 0;
            int d = 255;
            for (; d >= 0; --d) {
                unsigned c = hist[d];
                if (cum + c >= (unsigned)need) break;
                cum += c;
            }
            if (d < 0) d = 0;
            sh_need = need - (int)cum;
            sh_prefix = prefix | ((unsigned)d << shift);
        }
        __syncthreads();
        prefix = sh_prefix;
        need = sh_need;
        maskv |= (0xFFu << shift);
    }
    const unsigned T  = prefix;
    const unsigned Tl = fkey(kinv(T) - DELTA);
    const unsigned Th = fkey(kinv(T) + DELTA);

    #pragma unroll
    for (int i = 0; i < 16; ++i)
        #pragma unroll
        for (int j = 0; j < 4; ++j)
            if (key[i][j] >= Tl) {
                int p = atomicAdd(&nc_sh, 1);
                if (p < CAND_MAX) {
                    cand_idx[p] = (tid + i * 256) * 4 + j;
                    cand_key[p] = key[i][j];
                }
            }
    __syncthreads();
    int nc = nc_sh; if (nc > CAND_MAX) nc = CAND_MAX;

    if (tid < nc && cand_key[tid] > Th) atomicAdd(&nsure_sh, 1);
    __syncthreads();
    const int n_sure = nsure_sh;

    {
        const int lane = tid & 63, wave = tid >> 6;
        for (int c = wave; c < nc; c += 4) {
            if (cand_key[c] > Th) continue;
            const float* wr = &W[(size_t)cand_idx[c] * D_MODEL];
            double s = 0.0;
            #pragma unroll
            for (int e = 0; e < 16; ++e) {
                int d = lane + e * 64;
                s += (double)xs[d] * (double)wr[d];
            }
            #pragma unroll
            for (int o = 32; o; o >>= 1) s += __shfl_down(s, o);
            if (lane == 0) cand_val[c] = s + (double)be[cand_idx[c]];
        }
    }
    __syncthreads();

    if (tid < nc) {
        const unsigned ki = cand_key[tid];
        const int fi = cand_idx[tid];
        if (ki > Th) {
            int r = 0;
            for (int j = 0; j < nc; ++j)
                r += (cand_key[j] > Th) && (cand_idx[j] < fi);
            tk_idx[r] = fi;
            tk_val[r] = fmaxf(kinv(ki), 0.0f);
        } else {
            const double v = cand_val[tid];
            int r = 0;
            for (int j = 0; j < nc; ++j) {
                if (cand_key[j] > Th) continue;
                double vj = cand_val[j];
                r += (vj > v) || (vj == v && cand_idx[j] < fi);
            }
            if (r < K_TOP - n_sure) {
                tk_idx[n_sure + r] = fi;
                tk_val[n_sure + r] = fmaxf((float)v, 0.0f);
            }
        }
    }
    __syncthreads();

    #pragma unroll
    for (int i = 0; i < 16; ++i) {
        float ov[4];
        #pragma unroll
        for (int j = 0; j < 4; ++j) {
            unsigned k = key[i][j];
            int f = (tid + i * 256) * 4 + j;
            float val = 0.0f;
            if (k >= Tl) {
                for (int q = 0; q < K_TOP; ++q)
                    if (tk_idx[q] == f) { val = tk_val[q]; break; }
            }
            ov[j] = val;
        }
        float4 o; o.x = ov[0]; o.y = ov[1]; o.z = ov[2]; o.w = ov[3];
        ((float4*)srow)[tid + i * 256] = o;
    }
    __syncthreads();

    const int d4 = tid * 4;
    float4 a = *(const float4*)&bd[d4];
    if (USE_WB) {
        #pragma unroll 8
        for (int j = 0; j < K_TOP; ++j) {
            float v = tk_val[j];
            ushort4 w4 = *(const ushort4*)&Wb[(size_t)tk_idx[j] * D_MODEL + d4];
            a.x = fmaf(v, bf2f((unsigned)w4.x), a.x);
            a.y = fmaf(v, bf2f((unsigned)w4.y), a.y);
            a.z = fmaf(v, bf2f((unsigned)w4.z), a.z);
            a.w = fmaf(v, bf2f((unsigned)w4.w), a.w);
        }
    } else {
        #pragma unroll 8
        for (int j = 0; j < K_TOP; ++j) {
            float v = tk_val[j];
            const float4 w = *(const float4*)&W[(size_t)tk_idx[j] * D_MODEL + d4];
            a.x = fmaf(v, w.x, a.x);
            a.y = fmaf(v, w.y, a.y);
            a.z = fmaf(v, w.z, a.z);
            a.w = fmaf(v, w.w, a.w);
        }
    }
    *(float4*)&recon[d4] = a;
}

extern "C" void kernel_launch(void* const* d_in, const int* in_sizes, int n_in,
                              void* d_out, int out_size, void* d_ws, size_t ws_size,
                              hipStream_t stream) {
    const float* x     = (const float*)d_in[0];
    const float* W_enc = (const float*)d_in[1];
    const float* b_enc = (const float*)d_in[2];
    const float* b_dec = (const float*)d_in[4];
    float* out = (float*)d_out;

    float* h_out_region = out + (size_t)N_TOK * D_MODEL;

    const size_t nx = (size_t)N_TOK * D_MODEL;
    const size_t nw = (size_t)N_FEAT * D_MODEL;
    const size_t bf_bytes  = (nx + nw) * sizeof(unsigned short);          // 40 MB
    const size_t h16_bytes = (size_t)N_TOK * N_FEAT * sizeof(unsigned short); // 128 MB

    if (ws_size >= bf_bytes + h16_bytes) {
        // ---- tier A: bf16 h in ws, 1024-thread topk
        unsigned short* Xb = (unsigned short*)d_ws;
        unsigned short* Wb = Xb + nx;
        unsigned short* h16 = (unsigned short*)((char*)d_ws + bf_bytes);
        cvt_bf16<<<(int)(nx / 4 / 256), 256, 0, stream>>>(x, Xb, (int)(nx / 4));
        cvt_bf16<<<(int)(nw / 4 / 256), 256, 0, stream>>>(W_enc, Wb, (int)(nw / 4));
        encode_mfma<true><<<(N_TOK / BM) * (N_FEAT / BN), 256, 0, stream>>>(Xb, Wb, b_enc, h16);
        topk_decode16<<<N_TOK, 1024, 0, stream>>>(h16, x, W_enc, Wb, b_enc, b_dec, out);
    } else if (ws_size >= bf_bytes) {
        // ---- tier B: f32 h in out region
        unsigned short* Xb = (unsigned short*)d_ws;
        unsigned short* Wb = Xb + nx;
        cvt_bf16<<<(int)(nx / 4 / 256), 256, 0, stream>>>(x, Xb, (int)(nx / 4));
        cvt_bf16<<<(int)(nw / 4 / 256), 256, 0, stream>>>(W_enc, Wb, (int)(nw / 4));
        encode_mfma<false><<<(N_TOK / BM) * (N_FEAT / BN), 256, 0, stream>>>(Xb, Wb, b_enc, h_out_region);
        topk_decode<true><<<N_TOK, 256, 0, stream>>>(h_out_region, x, W_enc, Wb, b_enc, b_dec, out);
    } else {
        // ---- tier C: pure f32
        encode_gemm<<<(N_TOK / 64) * (N_FEAT / 64), 256, 0, stream>>>(x, W_enc, b_enc, h_out_region);
        topk_decode<false><<<N_TOK, 256, 0, stream>>>(h_out_region, x, W_enc, nullptr, b_enc, b_dec, out);
    }
}

// Round 7
// 1000.005 us; speedup vs baseline: 1.1222x; 1.0147x over previous
//
#include <hip/hip_runtime.h>

#define D_MODEL 1024
#define N_FEAT  16384
#define N_TOK   4096
#define K_TOP   64
#define CAND_MAX 256
#define DELTA    0.03f

#define BM 128
#define BN 128
#define BK 64

typedef __attribute__((ext_vector_type(8))) short bf16x8;
typedef __attribute__((ext_vector_type(8))) unsigned short u16x8;
typedef __attribute__((ext_vector_type(4))) float f32x4;

// ---- monotonic float<->uint keys ----
__device__ __forceinline__ unsigned fkey(float f) {
    unsigned b = __float_as_uint(f);
    return (b & 0x80000000u) ? ~b : (b | 0x80000000u);
}
__device__ __forceinline__ float kinv(unsigned k) {
    unsigned b = (k & 0x80000000u) ? (k ^ 0x80000000u) : ~k;
    return __uint_as_float(b);
}
// f32 -> bf16 bits, RNE
__device__ __forceinline__ unsigned short f2bf(float f) {
    unsigned u = __float_as_uint(f);
    return (unsigned short)((u + 0x7FFFu + ((u >> 16) & 1u)) >> 16);
}
__device__ __forceinline__ float bf2f(unsigned u) {
    return __uint_as_float(u << 16);
}
// 16-bit monotonic key over bf16 bits
__device__ __forceinline__ unsigned fkey16(unsigned b) {
    return (b & 0x8000u) ? (~b & 0xFFFFu) : (b | 0x8000u);
}
__device__ __forceinline__ float kval16(unsigned k) {
    unsigned b = (k & 0x8000u) ? (k ^ 0x8000u) : (~k & 0xFFFFu);
    return bf2f(b);
}
__device__ __forceinline__ unsigned fkey16f(float v) { return fkey16((unsigned)f2bf(v)); }

__device__ __forceinline__ void gload_lds16(const void* g, void* l) {
    __builtin_amdgcn_global_load_lds(
        (const __attribute__((address_space(1))) void*)g,
        (__attribute__((address_space(3))) void*)l, 16, 0, 0);
}

// =====================================================================
// Prep: f32 -> bf16 (RNE)
// =====================================================================
__global__ __launch_bounds__(256)
void cvt_bf16(const float* __restrict__ s, unsigned short* __restrict__ d, int n4)
{
    int i = blockIdx.x * 256 + threadIdx.x;
    if (i < n4) {
        float4 v = ((const float4*)s)[i];
        ushort4 o;
        o.x = f2bf(v.x); o.y = f2bf(v.y); o.z = f2bf(v.z); o.w = f2bf(v.w);
        ((ushort4*)d)[i] = o;
    }
}

// =====================================================================
// Kernel 1: bf16 MFMA encode GEMM (m97 structure); h out as bf16 or f32
// =====================================================================
template<bool B16OUT>
__global__ __launch_bounds__(256)
void encode_mfma(const unsigned short* __restrict__ Xb,
                 const unsigned short* __restrict__ Wb,
                 const float* __restrict__ be, void* __restrict__ hout)
{
    __shared__ unsigned short Al[BM * BK];
    __shared__ unsigned short Bl[BN * BK];

    const int nwg = gridDim.x;
    const int per = nwg >> 3;
    const int sw  = (blockIdx.x & 7) * per + (blockIdx.x >> 3);
    const int bm  = sw / (N_FEAT / BN);
    const int bn  = sw % (N_FEAT / BN);

    const int tid  = threadIdx.x;
    const int wid  = tid >> 6;
    const int lane = tid & 63;
    const int wr   = wid >> 1, wc = wid & 1;

    const size_t Abase = (size_t)(bm * BM) * D_MODEL;
    const size_t Bbase = (size_t)(bn * BN) * D_MODEL;

    f32x4 acc[4][4];
    #pragma unroll
    for (int m = 0; m < 4; ++m)
        #pragma unroll
        for (int n = 0; n < 4; ++n)
            acc[m][n] = (f32x4){0.f, 0.f, 0.f, 0.f};

    const int srow = (lane >> 3);
    const int scol = (lane & 7) * 8;

    for (int k0 = 0; k0 < D_MODEL; k0 += BK) {
        #pragma unroll
        for (int c4 = 0; c4 < 4; ++c4) {
            const int c   = wid * 4 + c4;
            const int row = c * 8 + srow;
            gload_lds16(Xb + Abase + (size_t)row * D_MODEL + k0 + scol, &Al[c * 512]);
            gload_lds16(Wb + Bbase + (size_t)row * D_MODEL + k0 + scol, &Bl[c * 512]);
        }
        __syncthreads();

        bf16x8 af[2][4], bf[2][4];
        const int kc = (lane >> 4) * 8;
        #pragma unroll
        for (int ks = 0; ks < 2; ++ks) {
            #pragma unroll
            for (int m = 0; m < 4; ++m)
                af[ks][m] = *(const bf16x8*)&Al[(wr * 64 + m * 16 + (lane & 15)) * BK + ks * 32 + kc];
            #pragma unroll
            for (int n = 0; n < 4; ++n)
                bf[ks][n] = *(const bf16x8*)&Bl[(wc * 64 + n * 16 + (lane & 15)) * BK + ks * 32 + kc];
        }
        #pragma unroll
        for (int ks = 0; ks < 2; ++ks)
            #pragma unroll
            for (int m = 0; m < 4; ++m)
                #pragma unroll
                for (int n = 0; n < 4; ++n)
                    acc[m][n] = __builtin_amdgcn_mfma_f32_16x16x32_bf16(af[ks][m], bf[ks][n], acc[m][n], 0, 0, 0);
        __syncthreads();
    }

    const int c0 = bn * BN + wc * 64 + (lane & 15);
    #pragma unroll
    for (int m = 0; m < 4; ++m) {
        const int r0 = bm * BM + wr * 64 + m * 16 + (lane >> 4) * 4;
        #pragma unroll
        for (int n = 0; n < 4; ++n) {
            const int col = c0 + n * 16;
            const float bias = be[col];
            #pragma unroll
            for (int r = 0; r < 4; ++r) {
                float v = acc[m][n][r] + bias;
                if (B16OUT)
                    ((unsigned short*)hout)[(size_t)(r0 + r) * N_FEAT + col] = f2bf(v);
                else
                    ((float*)hout)[(size_t)(r0 + r) * N_FEAT + col] = v;
            }
        }
    }
}

// =====================================================================
// Kernel 1 (fallback): f32 vector-ALU tiled GEMM
// =====================================================================
__global__ __launch_bounds__(256)
void encode_gemm(const float* __restrict__ x, const float* __restrict__ W,
                 const float* __restrict__ be, float* __restrict__ h)
{
    __shared__ float As[32][68];
    __shared__ float Bs[32][68];

    const int bm = blockIdx.x % (N_TOK / 64);
    const int bn = blockIdx.x / (N_TOK / 64);
    const int tid = threadIdx.x;
    const int tx = tid & 15, ty = tid >> 4;

    const float* Ab = x + (size_t)(bm * 64) * D_MODEL;
    const float* Bb = W + (size_t)(bn * 64) * D_MODEL;

    float acc[4][4] = {};

    for (int k0 = 0; k0 < D_MODEL; k0 += 32) {
        #pragma unroll
        for (int i = 0; i < 8; ++i) {
            int e = tid + i * 256;
            int kk = e & 31, m = e >> 5;
            As[kk][m] = Ab[(size_t)m * D_MODEL + k0 + kk];
            Bs[kk][m] = Bb[(size_t)m * D_MODEL + k0 + kk];
        }
        __syncthreads();
        #pragma unroll
        for (int kk = 0; kk < 32; ++kk) {
            float4 a4 = *(const float4*)&As[kk][ty * 4];
            float4 b4 = *(const float4*)&Bs[kk][tx * 4];
            float a[4] = {a4.x, a4.y, a4.z, a4.w};
            float b[4] = {b4.x, b4.y, b4.z, b4.w};
            #pragma unroll
            for (int i = 0; i < 4; ++i)
                #pragma unroll
                for (int j = 0; j < 4; ++j)
                    acc[i][j] = fmaf(a[i], b[j], acc[i][j]);
        }
        __syncthreads();
    }

    const int rowb = bm * 64 + ty * 4;
    const int colb = bn * 64 + tx * 4;
    float4 bev = *(const float4*)&be[colb];
    float bb[4] = {bev.x, bev.y, bev.z, bev.w};
    #pragma unroll
    for (int i = 0; i < 4; ++i) {
        float4 o;
        o.x = acc[i][0] + bb[0];
        o.y = acc[i][1] + bb[1];
        o.z = acc[i][2] + bb[2];
        o.w = acc[i][3] + bb[3];
        *(float4*)&h[(size_t)(rowb + i) * N_FEAT + colb] = o;
    }
}

// =====================================================================
// Kernel 2 (fast): per-row top-64 from bf16 h. 1024 threads/row.
//  Ballot-popcount binary search for the 64th-largest 16-bit key
//  (NO LDS atomics, 1 barrier/iter x 16 iters), f64 refinement of the
//  +/-DELTA band, streaming nt writes, grouped decode with LDS reduce.
// =====================================================================
__global__ __launch_bounds__(1024, 8)
void topk_decode16(const unsigned short* __restrict__ hb,
                   const float* __restrict__ x, const float* __restrict__ W,
                   const unsigned short* __restrict__ Wb,
                   const float* __restrict__ be, const float* __restrict__ bd,
                   float* __restrict__ out)
{
    const int row  = blockIdx.x;
    const int tid  = threadIdx.x;
    const int lane = tid & 63, wid = tid >> 6;

    float* recon = out + (size_t)row * D_MODEL;
    float* srow  = out + (size_t)N_TOK * D_MODEL + (size_t)row * N_FEAT;
    const unsigned short* hr = hb + (size_t)row * N_FEAT;

    __shared__ float xs[D_MODEL];
    __shared__ int      cand_idx[CAND_MAX];
    __shared__ unsigned cand_key[CAND_MAX];
    __shared__ double   cand_val[CAND_MAX];
    __shared__ int   tk_idx[K_TOP];
    __shared__ float tk_val[K_TOP];
    __shared__ f32x4 part[4][256];
    __shared__ int wavecnt[2][16];
    __shared__ int nc_sh, nsure_sh;

    // ---- load 16 bf16 h elems -> 16-bit monotonic keys
    unsigned key[16];
    {
        u16x8 a = *(const u16x8*)&hr[tid * 16];
        u16x8 b = *(const u16x8*)&hr[tid * 16 + 8];
        #pragma unroll
        for (int j = 0; j < 8; ++j) {
            key[j]     = fkey16((unsigned)(unsigned short)a[j]);
            key[8 + j] = fkey16((unsigned)(unsigned short)b[j]);
        }
    }
    if (tid < 256)
        *(float4*)&xs[tid * 4] = *(const float4*)&x[(size_t)row * D_MODEL + tid * 4];
    if (tid == 0) { nc_sh = 0; nsure_sh = 0; }
    if (tid < K_TOP) { tk_idx[tid] = 0; tk_val[tid] = 0.f; }
    __syncthreads();

    // ---- binary search for T = 64th-largest key; cnt via ballot popcount
    unsigned lo = 0, hi = 65535;
    #pragma unroll
    for (int it = 0; it < 16; ++it) {
        const unsigned mid = (lo + hi + 1) >> 1;
        int c = 0;
        #pragma unroll
        for (int i = 0; i < 16; ++i)
            c += __popcll(__ballot(key[i] >= mid));
        if (lane == 0) wavecnt[it & 1][wid] = c;   // c is wave-uniform
        __syncthreads();
        int tot = 0;
        #pragma unroll
        for (int w = 0; w < 16; ++w) tot += wavecnt[it & 1][w];
        if (tot >= K_TOP) lo = mid; else hi = mid - 1;
    }
    const unsigned T    = lo;
    const float    Tval = kval16(T);
    const unsigned Tl   = fkey16f(Tval - DELTA);
    const unsigned Th   = fkey16f(Tval + DELTA);

    // ---- collect candidates: key >= Tl (true top-64 always inside)
    #pragma unroll
    for (int i = 0; i < 16; ++i)
        if (key[i] >= Tl) {
            int p = atomicAdd(&nc_sh, 1);
            if (p < CAND_MAX) {
                cand_idx[p] = tid * 16 + i;
                cand_key[p] = key[i];
            }
        }
    __syncthreads();
    int nc = nc_sh; if (nc > CAND_MAX) nc = CAND_MAX;
    if (tid < nc && cand_key[tid] > Th) atomicAdd(&nsure_sh, 1);
    __syncthreads();
    const int n_sure = nsure_sh;

    // ---- f64 refinement of the ambiguous band only (from exact f32 inputs)
    for (int c = wid; c < nc; c += 16) {
        if (cand_key[c] > Th) continue;
        const float* wr = &W[(size_t)cand_idx[c] * D_MODEL];
        double s = 0.0;
        #pragma unroll
        for (int e = 0; e < 16; ++e) {
            int d = lane + e * 64;
            s += (double)xs[d] * (double)wr[d];
        }
        #pragma unroll
        for (int o = 32; o; o >>= 1) s += __shfl_down(s, o);
        if (lane == 0) cand_val[c] = s + (double)be[cand_idx[c]];
    }
    __syncthreads();

    // ---- deterministic slot assignment
    if (tid < nc) {
        const unsigned ki = cand_key[tid];
        const int fi = cand_idx[tid];
        if (ki > Th) {                       // provably in top-64
            int r = 0;
            for (int j = 0; j < nc; ++j)
                r += (cand_key[j] > Th) && (cand_idx[j] < fi);
            tk_idx[r] = fi;
            tk_val[r] = fmaxf(kval16(ki), 0.f);
        } else {                             // exact f64 rank in the band
            const double v = cand_val[tid];
            int r = 0;
            for (int j = 0; j < nc; ++j) {
                if (cand_key[j] > Th) continue;
                double vj = cand_val[j];
                r += (vj > v) || (vj == v && cand_idx[j] < fi);
            }
            if (r < K_TOP - n_sure) {
                tk_idx[n_sure + r] = fi;
                tk_val[n_sure + r] = fmaxf((float)v, 0.f);
            }
        }
    }
    __syncthreads();

    // ---- streaming sparse-row write (zeros + selected values), nontemporal
    #pragma unroll
    for (int q = 0; q < 4; ++q) {
        f32x4 o;
        #pragma unroll
        for (int j = 0; j < 4; ++j) {
            unsigned k = key[q * 4 + j];
            float val = 0.f;
            if (k >= Tl) {                   // rare (~95/16384)
                int f = tid * 16 + q * 4 + j;
                for (int m = 0; m < K_TOP; ++m)
                    if (tk_idx[m] == f) { val = tk_val[m]; break; }
            }
            o[j] = val;
        }
        __builtin_nontemporal_store(o, (f32x4*)srow + tid * 4 + q);
    }

    // ---- decode: 4 groups x 16 rows, LDS partial reduce
    {
        const int g = tid >> 8, t = tid & 255;
        const int d4 = t * 4;
        f32x4 a = (f32x4){0.f, 0.f, 0.f, 0.f};
        #pragma unroll 4
        for (int jj = 0; jj < 16; ++jj) {
            const int j = g * 16 + jj;
            const float v = tk_val[j];
            ushort4 w4 = *(const ushort4*)&Wb[(size_t)tk_idx[j] * D_MODEL + d4];
            a[0] = fmaf(v, bf2f((unsigned)w4.x), a[0]);
            a[1] = fmaf(v, bf2f((unsigned)w4.y), a[1]);
            a[2] = fmaf(v, bf2f((unsigned)w4.z), a[2]);
            a[3] = fmaf(v, bf2f((unsigned)w4.w), a[3]);
        }
        part[g][t] = a;
    }
    __syncthreads();
    if (tid < 256) {
        f32x4 r = part[0][tid];
        #pragma unroll
        for (int g = 1; g < 4; ++g) {
            f32x4 p = part[g][tid];
            r[0] += p[0]; r[1] += p[1]; r[2] += p[2]; r[3] += p[3];
        }
        float4 bdv = *(const float4*)&bd[tid * 4];
        f32x4 o;
        o[0] = r[0] + bdv.x; o[1] = r[1] + bdv.y;
        o[2] = r[2] + bdv.z; o[3] = r[3] + bdv.w;
        __builtin_nontemporal_store(o, (f32x4*)recon + tid);
    }
}

// =====================================================================
// Kernel 2 (fallback, f32 h): 256 threads/row, f32 radix version
// =====================================================================
template<bool USE_WB>
__global__ __launch_bounds__(256)
void topk_decode(const float* __restrict__ hsrc,
                 const float* __restrict__ x, const float* __restrict__ W,
                 const unsigned short* __restrict__ Wb,
                 const float* __restrict__ be, const float* __restrict__ bd,
                 float* __restrict__ out)
{
    const int row = blockIdx.x;
    const int tid = threadIdx.x;
    float* recon = out + (size_t)row * D_MODEL;
    float* srow  = out + (size_t)N_TOK * D_MODEL + (size_t)row * N_FEAT;
    const float* hr = hsrc + (size_t)row * N_FEAT;

    unsigned key[16][4];
    #pragma unroll
    for (int i = 0; i < 16; ++i) {
        float4 v = ((const float4*)hr)[tid + i * 256];
        key[i][0] = fkey(v.x); key[i][1] = fkey(v.y);
        key[i][2] = fkey(v.z); key[i][3] = fkey(v.w);
    }

    __shared__ unsigned hist[256];
    __shared__ unsigned sh_prefix;
    __shared__ int sh_need;
    __shared__ float xs[D_MODEL];
    __shared__ int      cand_idx[CAND_MAX];
    __shared__ unsigned cand_key[CAND_MAX];
    __shared__ double   cand_val[CAND_MAX];
    __shared__ int nc_sh, nsure_sh;
    __shared__ int   tk_idx[K_TOP];
    __shared__ float tk_val[K_TOP];

    *(float4*)&xs[tid * 4] = *(const float4*)&x[(size_t)row * D_MODEL + tid * 4];
    if (tid == 0) { nc_sh = 0; nsure_sh = 0; }
    if (tid < K_TOP) { tk_val[tid] = 0.0f; tk_idx[tid] = -1; }

    unsigned prefix = 0, maskv = 0;
    int need = K_TOP;
    for (int pass = 0; pass < 4; ++pass) {
        const int shift = 24 - 8 * pass;
        hist[tid] = 0;
        __syncthreads();
        #pragma unroll
        for (int i = 0; i < 16; ++i)
            #pragma unroll
            for (int j = 0; j < 4; ++j) {
                unsigned k = key[i][j];
                if ((k & maskv) == prefix)
                    atomicAdd(&hist[(k >> shift) & 255u], 1u);
            }
        __syncthreads();
        if (tid == 0) {
            unsigned cum = 0;
            int d = 255;
            for (; d >= 0; --d) {
                unsigned c = hist[d];
                if (cum + c >= (unsigned)need) break;
                cum += c;
            }
            if (d < 0) d = 0;
            sh_need = need - (int)cum;
            sh_prefix = prefix | ((unsigned)d << shift);
        }
        __syncthreads();
        prefix = sh_prefix;
        need = sh_need;
        maskv |= (0xFFu << shift);
    }
    const unsigned T  = prefix;
    const unsigned Tl = fkey(kinv(T) - DELTA);
    const unsigned Th = fkey(kinv(T) + DELTA);

    #pragma unroll
    for (int i = 0; i < 16; ++i)
        #pragma unroll
        for (int j = 0; j < 4; ++j)
            if (key[i][j] >= Tl) {
                int p = atomicAdd(&nc_sh, 1);
                if (p < CAND_MAX) {
                    cand_idx[p] = (tid + i * 256) * 4 + j;
                    cand_key[p] = key[i][j];
                }
            }
    __syncthreads();
    int nc = nc_sh; if (nc > CAND_MAX) nc = CAND_MAX;

    if (tid < nc && cand_key[tid] > Th) atomicAdd(&nsure_sh, 1);
    __syncthreads();
    const int n_sure = nsure_sh;

    {
        const int lane = tid & 63, wave = tid >> 6;
        for (int c = wave; c < nc; c += 4) {
            if (cand_key[c] > Th) continue;
            const float* wr = &W[(size_t)cand_idx[c] * D_MODEL];
            double s = 0.0;
            #pragma unroll
            for (int e = 0; e < 16; ++e) {
                int d = lane + e * 64;
                s += (double)xs[d] * (double)wr[d];
            }
            #pragma unroll
            for (int o = 32; o; o >>= 1) s += __shfl_down(s, o);
            if (lane == 0) cand_val[c] = s + (double)be[cand_idx[c]];
        }
    }
    __syncthreads();

    if (tid < nc) {
        const unsigned ki = cand_key[tid];
        const int fi = cand_idx[tid];
        if (ki > Th) {
            int r = 0;
            for (int j = 0; j < nc; ++j)
                r += (cand_key[j] > Th) && (cand_idx[j] < fi);
            tk_idx[r] = fi;
            tk_val[r] = fmaxf(kinv(ki), 0.0f);
        } else {
            const double v = cand_val[tid];
            int r = 0;
            for (int j = 0; j < nc; ++j) {
                if (cand_key[j] > Th) continue;
                double vj = cand_val[j];
                r += (vj > v) || (vj == v && cand_idx[j] < fi);
            }
            if (r < K_TOP - n_sure) {
                tk_idx[n_sure + r] = fi;
                tk_val[n_sure + r] = fmaxf((float)v, 0.0f);
            }
        }
    }
    __syncthreads();

    #pragma unroll
    for (int i = 0; i < 16; ++i) {
        float ov[4];
        #pragma unroll
        for (int j = 0; j < 4; ++j) {
            unsigned k = key[i][j];
            int f = (tid + i * 256) * 4 + j;
            float val = 0.0f;
            if (k >= Tl) {
                for (int q = 0; q < K_TOP; ++q)
                    if (tk_idx[q] == f) { val = tk_val[q]; break; }
            }
            ov[j] = val;
        }
        float4 o; o.x = ov[0]; o.y = ov[1]; o.z = ov[2]; o.w = ov[3];
        ((float4*)srow)[tid + i * 256] = o;
    }
    __syncthreads();

    const int d4 = tid * 4;
    float4 a = *(const float4*)&bd[d4];
    if (USE_WB) {
        #pragma unroll 8
        for (int j = 0; j < K_TOP; ++j) {
            float v = tk_val[j];
            ushort4 w4 = *(const ushort4*)&Wb[(size_t)tk_idx[j] * D_MODEL + d4];
            a.x = fmaf(v, bf2f((unsigned)w4.x), a.x);
            a.y = fmaf(v, bf2f((unsigned)w4.y), a.y);
            a.z = fmaf(v, bf2f((unsigned)w4.z), a.z);
            a.w = fmaf(v, bf2f((unsigned)w4.w), a.w);
        }
    } else {
        #pragma unroll 8
        for (int j = 0; j < K_TOP; ++j) {
            float v = tk_val[j];
            const float4 w = *(const float4*)&W[(size_t)tk_idx[j] * D_MODEL + d4];
            a.x = fmaf(v, w.x, a.x);
            a.y = fmaf(v, w.y, a.y);
            a.z = fmaf(v, w.z, a.z);
            a.w = fmaf(v, w.w, a.w);
        }
    }
    *(float4*)&recon[d4] = a;
}

extern "C" void kernel_launch(void* const* d_in, const int* in_sizes, int n_in,
                              void* d_out, int out_size, void* d_ws, size_t ws_size,
                              hipStream_t stream) {
    const float* x     = (const float*)d_in[0];
    const float* W_enc = (const float*)d_in[1];
    const float* b_enc = (const float*)d_in[2];
    const float* b_dec = (const float*)d_in[4];
    float* out = (float*)d_out;

    float* h_out_region = out + (size_t)N_TOK * D_MODEL;

    const size_t nx = (size_t)N_TOK * D_MODEL;
    const size_t nw = (size_t)N_FEAT * D_MODEL;
    const size_t bf_bytes  = (nx + nw) * sizeof(unsigned short);          // 40 MB
    const size_t h16_bytes = (size_t)N_TOK * N_FEAT * sizeof(unsigned short); // 128 MB

    if (ws_size >= bf_bytes + h16_bytes) {
        // ---- tier A: bf16 h in ws, 1024-thread ballot-search topk
        unsigned short* Xb = (unsigned short*)d_ws;
        unsigned short* Wb = Xb + nx;
        unsigned short* h16 = (unsigned short*)((char*)d_ws + bf_bytes);
        cvt_bf16<<<(int)(nx / 4 / 256), 256, 0, stream>>>(x, Xb, (int)(nx / 4));
        cvt_bf16<<<(int)(nw / 4 / 256), 256, 0, stream>>>(W_enc, Wb, (int)(nw / 4));
        encode_mfma<true><<<(N_TOK / BM) * (N_FEAT / BN), 256, 0, stream>>>(Xb, Wb, b_enc, h16);
        topk_decode16<<<N_TOK, 1024, 0, stream>>>(h16, x, W_enc, Wb, b_enc, b_dec, out);
    } else if (ws_size >= bf_bytes) {
        // ---- tier B: f32 h in out region
        unsigned short* Xb = (unsigned short*)d_ws;
        unsigned short* Wb = Xb + nx;
        cvt_bf16<<<(int)(nx / 4 / 256), 256, 0, stream>>>(x, Xb, (int)(nx / 4));
        cvt_bf16<<<(int)(nw / 4 / 256), 256, 0, stream>>>(W_enc, Wb, (int)(nw / 4));
        encode_mfma<false><<<(N_TOK / BM) * (N_FEAT / BN), 256, 0, stream>>>(Xb, Wb, b_enc, h_out_region);
        topk_decode<true><<<N_TOK, 256, 0, stream>>>(h_out_region, x, W_enc, Wb, b_enc, b_dec, out);
    } else {
        // ---- tier C: pure f32
        encode_gemm<<<(N_TOK / 64) * (N_FEAT / 64), 256, 0, stream>>>(x, W_enc, b_enc, h_out_region);
        topk_decode<false><<<N_TOK, 256, 0, stream>>>(h_out_region, x, W_enc, nullptr, b_enc, b_dec, out);
    }
}